// Round 1
// baseline (257.778 us; speedup 1.0000x reference)
//
#include <hip/hip_runtime.h>
#include <hip/hip_bf16.h>

typedef short bf16x8 __attribute__((ext_vector_type(8)));
typedef float f32x4 __attribute__((ext_vector_type(4)));

#define N_IMG 64
#define CIN   256
#define COUT  256
#define HH    28
#define WW    28
#define PH    30
#define PW    30
#define M_TOT (N_IMG*HH*WW)        // 50176
#define OUT_ELEMS (N_IMG*COUT*HH*WW) // 12845056

// workspace layout (bytes)
#define XT_ELEMS   ((size_t)N_IMG*PH*PW*CIN)       // 14745600 bf16
#define WT_OFF     (XT_ELEMS*2)                    // 29491200
#define WT_ELEMS   ((size_t)9*COUT*CIN)            // 589824 bf16
#define BQ_OFF     (WT_OFF + WT_ELEMS*2)           // 30670848

#define GLD16(g, l) __builtin_amdgcn_global_load_lds( \
    (const __attribute__((address_space(1))) void*)(g), \
    (__attribute__((address_space(3))) void*)(l), 16, 0, 0)

// ---------------------------------------------------------------------------
// Kernel 1: x int32 NCHW -> padded bf16 NHWC [N][30][30][256]
// one block per (n, padded-row py)
__global__ __launch_bounds__(256) void transform_x(const int* __restrict__ xq,
                                                   unsigned short* __restrict__ xt) {
    __shared__ float xs[CIN*29];   // padded stride 29 -> no bank conflicts
    const int b = blockIdx.x;
    const int n = b / PH, py = b % PH;
    const int t = threadIdx.x;
    unsigned short* dst = xt + ((size_t)(n*PH + py))*PW*CIN;
    if (py == 0 || py == PH-1) {
        for (int i = t; i < PW*CIN; i += 256) dst[i] = 0;
        return;
    }
    const int h = py - 1;
    const int* src = xq + (size_t)n*CIN*HH*WW + h*WW;
    for (int i = t; i < CIN*WW; i += 256) {
        const int ci = i / WW, w = i % WW;
        xs[ci*29 + w] = (float)src[ci*HH*WW + w];
    }
    __syncthreads();
    for (int i = t; i < PW*CIN; i += 256) {
        const int px = i / CIN, ci = i % CIN;
        float v = (px == 0 || px == PW-1) ? 0.f : xs[ci*29 + (px-1)];
        dst[px*CIN + ci] = (unsigned short)(__float_as_uint(v) >> 16);
    }
}

// ---------------------------------------------------------------------------
// Kernel 2: per-channel weight quant + bias quant + scale_out to d_out tail.
// wt layout: [tap(9)][co(256)][ci(256)] bf16   (values in [-128,127], exact)
__global__ __launch_bounds__(256) void quant_w(const float* __restrict__ weight,
                                               const float* __restrict__ scale_x,
                                               const float* __restrict__ bias,
                                               unsigned short* __restrict__ wt,
                                               int* __restrict__ bq,
                                               float* __restrict__ out_tail) {
    __shared__ float red[256];
    const int co = blockIdx.x, t = threadIdx.x;
    const float* wrow = weight + (size_t)co*CIN*9;
    float wv[9];
    float mx = 0.f;
    for (int it = 0; it < 9; ++it) {
        float v = wrow[it*256 + t];
        wv[it] = v;
        mx = fmaxf(mx, fabsf(v));
    }
    red[t] = mx;
    __syncthreads();
    for (int s = 128; s > 0; s >>= 1) {
        if (t < s) red[t] = fmaxf(red[t], red[t+s]);
        __syncthreads();
    }
    const float scale = fmaxf(red[0], 1e-8f) / 127.f;
    for (int it = 0; it < 9; ++it) {
        const int i = it*256 + t;          // index over [ci][r][s]
        const int ci = i / 9, rs = i % 9;
        float q = rintf(wv[it] / scale);   // rintf = round-half-even = jnp.round
        q = fminf(fmaxf(q, -128.f), 127.f);
        wt[((size_t)rs*COUT + co)*CIN + ci] = (unsigned short)(__float_as_uint(q) >> 16);
    }
    if (t == 0) {
        const float so = scale * scale_x[0];
        out_tail[co] = so;
        bq[co] = (int)rintf(bias[co] / so);
    }
}

// ---------------------------------------------------------------------------
// Kernel 3: implicit-GEMM conv. C[co][m] = sum_{tap,ci} W * X.
// Block tile: 64 co x 64 m, BK=32, 4 waves (2x2), mfma_f32_16x16x32_bf16.
// LDS: chunked [kc(4)][row(64)][8 bf16] so global_load_lds lands linearly and
// frag ds_read_b128 is fully contiguous per 16-lane group (conflict-free).
__global__ __launch_bounds__(256) void conv_mfma(const unsigned short* __restrict__ xt,
                                                 const unsigned short* __restrict__ wt,
                                                 const int* __restrict__ bq,
                                                 float* __restrict__ out) {
    __shared__ short Ash[2048];  // W tile: [kc][co_local][8]
    __shared__ short Bsh[2048];  // X tile: [kc][m_local][8]
    const int t = threadIdx.x;
    const int lane = t & 63, wid = t >> 6;
    const int wr = wid >> 1, wc = wid & 1;         // wave: rows(co) x cols(m)
    const int m0 = blockIdx.x * 64, co0 = blockIdx.y * 64;

    // per-lane staging sources
    const int m = m0 + lane;
    const int n = m / 784, hw = m % 784;
    const int h = hw / 28, w = hw % 28;
    const unsigned short* bsrc0 = xt + ((size_t)((n*PH + h)*PW + w))*CIN;
    const unsigned short* asrc0 = wt + (size_t)(co0 + lane)*CIN;

    f32x4 acc[2][2] = {};
    const int kg = lane >> 4, lr = lane & 15;

    for (int tap = 0; tap < 9; ++tap) {
        const int r = tap/3, s = tap - r*3;
        const unsigned short* bsrc_t = bsrc0 + (r*PW + s)*CIN;
        const unsigned short* asrc_t = asrc0 + (size_t)tap*COUT*CIN;
        for (int ci0 = 0; ci0 < CIN; ci0 += 32) {
            GLD16(asrc_t + ci0 + wid*8, Ash + wid*512);
            GLD16(bsrc_t + ci0 + wid*8, Bsh + wid*512);
            asm volatile("s_waitcnt vmcnt(0)" ::: "memory");
            __syncthreads();
            bf16x8 a0 = *(const bf16x8*)&Ash[kg*512 + (wr*32 +      lr)*8];
            bf16x8 a1 = *(const bf16x8*)&Ash[kg*512 + (wr*32 + 16 + lr)*8];
            bf16x8 b0 = *(const bf16x8*)&Bsh[kg*512 + (wc*32 +      lr)*8];
            bf16x8 b1 = *(const bf16x8*)&Bsh[kg*512 + (wc*32 + 16 + lr)*8];
            acc[0][0] = __builtin_amdgcn_mfma_f32_16x16x32_bf16(a0, b0, acc[0][0], 0,0,0);
            acc[0][1] = __builtin_amdgcn_mfma_f32_16x16x32_bf16(a0, b1, acc[0][1], 0,0,0);
            acc[1][0] = __builtin_amdgcn_mfma_f32_16x16x32_bf16(a1, b0, acc[1][0], 0,0,0);
            acc[1][1] = __builtin_amdgcn_mfma_f32_16x16x32_bf16(a1, b1, acc[1][1], 0,0,0);
            __syncthreads();
        }
    }

    // epilogue: D row = co (kg*4+rg), col = m (lr); writes are 64B runs
    for (int fm = 0; fm < 2; ++fm) {
        for (int fn = 0; fn < 2; ++fn) {
            const int co = co0 + wr*32 + fm*16 + kg*4;
            const int mm = m0 + wc*32 + fn*16 + lr;
            const int nn = mm / 784, hw2 = mm % 784;
            for (int rg = 0; rg < 4; ++rg) {
                const float v = acc[fm][fn][rg] + (float)bq[co + rg];
                out[((size_t)nn*COUT + co + rg)*784 + hw2] = v;
            }
        }
    }
}

// ---------------------------------------------------------------------------
extern "C" void kernel_launch(void* const* d_in, const int* in_sizes, int n_in,
                              void* d_out, int out_size, void* d_ws, size_t ws_size,
                              hipStream_t stream) {
    const int*   xq      = (const int*)d_in[0];
    const float* scale_x = (const float*)d_in[1];
    const float* weight  = (const float*)d_in[2];
    const float* bias    = (const float*)d_in[3];
    float* out = (float*)d_out;

    unsigned short* xt = (unsigned short*)d_ws;
    unsigned short* wt = (unsigned short*)((char*)d_ws + WT_OFF);
    int*            bq = (int*)((char*)d_ws + BQ_OFF);

    hipLaunchKernelGGL(transform_x, dim3(N_IMG*PH), dim3(256), 0, stream, xq, xt);
    hipLaunchKernelGGL(quant_w, dim3(COUT), dim3(256), 0, stream,
                       weight, scale_x, bias, wt, bq, out + OUT_ELEMS);
    hipLaunchKernelGGL(conv_mfma, dim3(M_TOT/64, COUT/64), dim3(256), 0, stream,
                       xt, wt, bq, out);
}

// Round 4
// 176.055 us; speedup vs baseline: 1.4642x; 1.4642x over previous
//
#include <hip/hip_runtime.h>
#include <hip/hip_bf16.h>

typedef short bf16x8 __attribute__((ext_vector_type(8)));
typedef float f32x4 __attribute__((ext_vector_type(4)));

#define N_IMG 64
#define CIN   256
#define COUT  256
#define HH    28
#define WW    28
#define PH    30
#define PW    30
#define M_TOT (N_IMG*HH*WW)          // 50176
#define OUT_ELEMS (N_IMG*COUT*HH*WW) // 12845056

// workspace layout (bytes)
#define XT_ELEMS   ((size_t)N_IMG*PH*PW*CIN)       // 14745600 bf16
#define WT_OFF     (XT_ELEMS*2)                    // 29491200
#define WT_ELEMS   ((size_t)9*COUT*CIN)            // 589824 bf16
#define BQ_OFF     (WT_OFF + WT_ELEMS*2)           // 30670848

#define GLD16(g, l) __builtin_amdgcn_global_load_lds( \
    (const __attribute__((address_space(1))) void*)(g), \
    (__attribute__((address_space(3))) void*)(l), 16, 0, 0)

// ---------------------------------------------------------------------------
// Kernel 1: x int32 NCHW -> padded bf16 NHWC [N][30][30][256]
__global__ __launch_bounds__(256) void transform_x(const int* __restrict__ xq,
                                                   unsigned short* __restrict__ xt) {
    __shared__ float xs[CIN*29];   // padded stride 29 -> no bank conflicts
    const int b = blockIdx.x;
    const int n = b / PH, py = b % PH;
    const int t = threadIdx.x;
    unsigned short* dst = xt + ((size_t)(n*PH + py))*PW*CIN;
    if (py == 0 || py == PH-1) {
        for (int i = t; i < PW*CIN; i += 256) dst[i] = 0;
        return;
    }
    const int h = py - 1;
    const int* src = xq + (size_t)n*CIN*HH*WW + h*WW;
    for (int i = t; i < CIN*WW; i += 256) {
        const int ci = i / WW, w = i % WW;
        xs[ci*29 + w] = (float)src[ci*HH*WW + w];
    }
    __syncthreads();
    for (int i = t; i < PW*CIN; i += 256) {
        const int px = i / CIN, ci = i % CIN;
        float v = (px == 0 || px == PW-1) ? 0.f : xs[ci*29 + (px-1)];
        dst[px*CIN + ci] = (unsigned short)(__float_as_uint(v) >> 16);
    }
}

// ---------------------------------------------------------------------------
// Kernel 2: per-channel weight quant + bias quant + scale_out to d_out tail.
// wt layout: [tap(9)][co(256)][ci(256)] bf16   (values in [-128,127], exact)
__global__ __launch_bounds__(256) void quant_w(const float* __restrict__ weight,
                                               const float* __restrict__ scale_x,
                                               const float* __restrict__ bias,
                                               unsigned short* __restrict__ wt,
                                               int* __restrict__ bq,
                                               float* __restrict__ out_tail) {
    __shared__ float red[256];
    const int co = blockIdx.x, t = threadIdx.x;
    const float* wrow = weight + (size_t)co*CIN*9;
    float wv[9];
    float mx = 0.f;
    for (int it = 0; it < 9; ++it) {
        float v = wrow[it*256 + t];
        wv[it] = v;
        mx = fmaxf(mx, fabsf(v));
    }
    red[t] = mx;
    __syncthreads();
    for (int s = 128; s > 0; s >>= 1) {
        if (t < s) red[t] = fmaxf(red[t], red[t+s]);
        __syncthreads();
    }
    const float scale = fmaxf(red[0], 1e-8f) / 127.f;
    for (int it = 0; it < 9; ++it) {
        const int i = it*256 + t;          // index over [ci][r][s]
        const int ci = i / 9, rs = i % 9;
        float q = rintf(wv[it] / scale);   // rintf = round-half-even = jnp.round
        q = fminf(fmaxf(q, -128.f), 127.f);
        wt[((size_t)rs*COUT + co)*CIN + ci] = (unsigned short)(__float_as_uint(q) >> 16);
    }
    if (t == 0) {
        const float so = scale * scale_x[0];
        out_tail[co] = so;
        bq[co] = (int)rintf(bias[co] / so);
    }
}

// ---------------------------------------------------------------------------
// Kernel 3: implicit-GEMM conv, m97 structure.
// C[co][m] = sum_{tap,ci} W[co][ci,tap] * X[ci,tap][m]
// Block tile: 128 co x 128 m, BK=32, 4 waves (2x2), each wave 64x64 (acc[4][4]).
// LDS (single-buffered, 16KB): chunked [kc(4)][row(128)][8 bf16] per operand so
// global_load_lds writes land linearly (slot c=t+round*256 -> kc=c>>7, row=c&127)
// and fragment ds_read_b128 is contiguous per 16-lane group (conflict-free).
__global__ __launch_bounds__(256) void conv_mfma(const unsigned short* __restrict__ xt,
                                                 const unsigned short* __restrict__ wt,
                                                 const int* __restrict__ bq,
                                                 float* __restrict__ out) {
    __shared__ short Ash[4096];  // W tile: 128 rows(co) x 32 k
    __shared__ short Bsh[4096];  // X tile: 128 rows(m)  x 32 k
    const int t = threadIdx.x;
    const int lane = t & 63, wid = t >> 6;
    const int wr = wid >> 1, wc = wid & 1;         // wave grid: 2 (co) x 2 (m)
    const int m0 = blockIdx.x * 128, co0 = blockIdx.y * 128;

    // staging geometry: slot c = t (+256 for round 1); kc = c>>7, row = c&127
    const int srow = (wid & 1)*64 + lane;          // staged row (both rounds)
    const int kc0  = wid >> 1;                     // round-0 k-chunk (round 1: +2)

    // per-thread global sources
    const int m = m0 + srow;
    const int n = m / 784, hw = m % 784;
    const int h = hw / 28, w = hw % 28;
    const unsigned short* bsrc0 = xt + ((size_t)((n*PH + h)*PW + w))*CIN + kc0*8;
    const unsigned short* asrc0 = wt + (size_t)(co0 + srow)*CIN + kc0*8;

    f32x4 acc[4][4] = {};
    const int kg = lane >> 4, lr = lane & 15;
    const int ar0 = (wr*64 + lr)*8 + kg*1024;      // A frag base (shorts)
    const int br0 = (wc*64 + lr)*8 + kg*1024;      // B frag base

    for (int tap = 0; tap < 9; ++tap) {
        const int r = tap/3, s = tap - r*3;
        const unsigned short* at = asrc0 + (size_t)tap*COUT*CIN;
        const unsigned short* bt = bsrc0 + (r*PW + s)*CIN;
        for (int ci0 = 0; ci0 < CIN; ci0 += 32) {
            GLD16(at + ci0,      Ash + wid*512);
            GLD16(at + ci0 + 16, Ash + 2048 + wid*512);
            GLD16(bt + ci0,      Bsh + wid*512);
            GLD16(bt + ci0 + 16, Bsh + 2048 + wid*512);
            asm volatile("s_waitcnt vmcnt(0)" ::: "memory");
            __syncthreads();
            bf16x8 af[4], bf[4];
#pragma unroll
            for (int f = 0; f < 4; ++f) {
                af[f] = *(const bf16x8*)&Ash[ar0 + f*128];
                bf[f] = *(const bf16x8*)&Bsh[br0 + f*128];
            }
#pragma unroll
            for (int fm = 0; fm < 4; ++fm)
#pragma unroll
                for (int fn = 0; fn < 4; ++fn)
                    acc[fm][fn] = __builtin_amdgcn_mfma_f32_16x16x32_bf16(
                        af[fm], bf[fn], acc[fm][fn], 0, 0, 0);
            __syncthreads();
        }
    }

    // epilogue: D row = co (kg*4+rg), col = m (lr); 64B coalesced runs
#pragma unroll
    for (int fm = 0; fm < 4; ++fm) {
        const int co = co0 + wr*64 + fm*16 + kg*4;
        float bqv[4];
#pragma unroll
        for (int rg = 0; rg < 4; ++rg) bqv[rg] = (float)bq[co + rg];
#pragma unroll
        for (int fn = 0; fn < 4; ++fn) {
            const int mm = m0 + wc*64 + fn*16 + lr;
            const int nn = mm / 784, hw2 = mm % 784;
#pragma unroll
            for (int rg = 0; rg < 4; ++rg)
                out[((size_t)nn*COUT + co + rg)*784 + hw2] = acc[fm][fn][rg] + bqv[rg];
        }
    }
}

// ---------------------------------------------------------------------------
extern "C" void kernel_launch(void* const* d_in, const int* in_sizes, int n_in,
                              void* d_out, int out_size, void* d_ws, size_t ws_size,
                              hipStream_t stream) {
    const int*   xq      = (const int*)d_in[0];
    const float* scale_x = (const float*)d_in[1];
    const float* weight  = (const float*)d_in[2];
    const float* bias    = (const float*)d_in[3];
    float* out = (float*)d_out;

    unsigned short* xt = (unsigned short*)d_ws;
    unsigned short* wt = (unsigned short*)((char*)d_ws + WT_OFF);
    int*            bq = (int*)((char*)d_ws + BQ_OFF);

    hipLaunchKernelGGL(transform_x, dim3(N_IMG*PH), dim3(256), 0, stream, xq, xt);
    hipLaunchKernelGGL(quant_w, dim3(COUT), dim3(256), 0, stream,
                       weight, scale_x, bias, wt, bq, out + OUT_ELEMS);
    hipLaunchKernelGGL(conv_mfma, dim3(M_TOT/128, COUT/128), dim3(256), 0, stream,
                       xt, wt, bq, out);
}